// Round 6
// baseline (143.806 us; speedup 1.0000x reference)
//
#include <hip/hip_runtime.h>
#include <hip/hip_bf16.h>

// Fused 34->128->128->1 MLP, bf16 MFMA.
// R16 "wave-solo": each wave processes 16 points end-to-end with ALL
// weights resident in the unified VGPR/AGPR file. No H exchange, no
// barriers, no PART — the 4-way hidden split (R7-R15) forced ~35 DS
// instrs/wave-tile + 3 block barriers; R15 proved the kernel is gap-bound
// (VALUBusy 45->26 with dur unchanged; no pipe >33%).
// Structure per wave (block = 64 thr, grid 1024, 1 wave/SIMD, lb(64,1)):
//  - w0t[8][2] (64 regs), w1t[8][4] (128), b0q/b1q (64), w2f[4] (16):
//    full replication, ~352 combined peak < 512 budget at 1 wave/EU.
//  - R8a identity, per-wave: phys h = (ob>>1)*32 + q*8 + (ob&1)*4 + r;
//    L0 C/D frag pairs pk2c-pack into L1 B-frags (h1f[4]) IN REGISTERS;
//    same packing feeds L2 (W2 in A row 0, D[0][cl] = dot).
//  - LDS = wave-private A0 double-buffer only (2x16x72 shorts = 4.6KB):
//    stage(c+1) -> buf^1 while L0 reads buf. In-order per-wave DS queue
//    + compiler lgkmcnt gives correctness with ZERO barriers.
//  - 2-deep software pipeline: iter c stages c+S (gathers g*, frA, xvA
//    loaded last iter), issues gathers for c+2S (from feB), scalar loads
//    for c+3S. All HBM/L2 latency hidden under MFMA of tile c.
// Diet kept (verified R11-R15, absmax 0.00390625): pk2c clamp-fused cvt,
// L2-as-MFMA, biases ride first MFMA C operand.
// Spill tell: WRITE_SIZE == 3906KB <=> clean. If the allocator chases a
// 2-wave rung and spills (R12/R13 lesson), fall back to 2-wave pair-split.

using bf16x8 = __attribute__((ext_vector_type(8))) short;   // 8 bf16 = 4 VGPRs
using f32x4  = __attribute__((ext_vector_type(4))) float;   // MFMA C/D

#define NPTS    1000000
#define NUMEMB  6572
#define HID     128
#define A0S     72          // A0 row stride in bf16 (144B, 16B-aligned rows)
#define CHUNKS  62500       // NPTS / 16 points-per-wave-tile
#define LASTC   (CHUNKS - 1)
#define NBLOCKS 1024        // 1 wave/block; 4 blocks/CU at 1 wave/SIMD
#define STRIDE  1024

__device__ __forceinline__ unsigned short bf16r(float f) {
    unsigned u;
    __builtin_memcpy(&u, &f, 4);
    u = (u + 0x7fffu + ((u >> 16) & 1u)) >> 16;
    return (unsigned short)u;
}
__device__ __forceinline__ unsigned pk2(float a, float b) {
    // packed RNE f32x2 -> bf16x2 (v_cvt_pk_bf16_f32 on gfx950)
    float2 f2; f2.x = a; f2.y = b;
    __hip_bfloat162 h = __float22bfloat162_rn(f2);
    unsigned u;
    __builtin_memcpy(&u, &h, 4);
    return u;
}
__device__ __forceinline__ unsigned pk2c(float a, float b) {
    // packed cvt with VOP3 clamp: result clamped to [0,1] — fuses clamp01
    unsigned r;
    asm("v_cvt_pk_bf16_f32 %0, %1, %2 clamp" : "=v"(r) : "v"(a), "v"(b));
    return r;
}

__global__ __launch_bounds__(64, 1)
void mlp_fused(const float* __restrict__ x,
               const float* __restrict__ emb,
               const float* __restrict__ em_table,
               const float* __restrict__ W0, const float* __restrict__ b0,
               const float* __restrict__ W1, const float* __restrict__ b1,
               const float* __restrict__ W2, const float* __restrict__ b2,
               float* __restrict__ out)
{
    __shared__ __align__(16) unsigned short A0[2 * 16 * A0S]; // double-buffer

    const int lane = threadIdx.x;
    const int q  = lane >> 4;    // MFMA quad
    const int cl = lane & 15;    // MFMA col/row-within-quad
    const int p  = lane >> 2;    // staging: point 0..15
    const int s  = lane & 3;     // staging: 8-dim segment

    // zero both buffers once (cols 34..63 must read 0; stage writes 0..33)
    for (int i = lane; i < 2 * 16 * A0S; i += 64) A0[i] = 0;

    // ---- one-time: ALL weights as A-fragments (permuted cols) ----
    // Output block ob in 0..7 -> phys h = (ob>>1)*32 + q*8 + (ob&1)*4 + r;
    // A-frag column for m=cl: col(ob) = (ob>>1)*32 + (cl>>2)*8 + (ob&1)*4 + (cl&3).
    bf16x8 w0t[8][2];   // [ob][kt]  W0 rows: k<32 em, k32/k33 = x0/x1
    #pragma unroll
    for (int ob = 0; ob < 8; ++ob) {
        const int col = (ob >> 1) * 32 + (cl >> 2) * 8 + (ob & 1) * 4 + (cl & 3);
        #pragma unroll
        for (int kt = 0; kt < 2; ++kt) {
            bf16x8 v;
            #pragma unroll
            for (int e = 0; e < 8; ++e) {
                const int k = kt * 32 + q * 8 + e;
                float val = 0.f;
                if (k < 32)       val = W0[(2 + k) * HID + col];
                else if (k == 32) val = W0[0 * HID + col];
                else if (k == 33) val = W0[1 * HID + col];
                v[e] = (short)bf16r(val);
            }
            w0t[ob][kt] = v;
        }
    }
    bf16x8 w1t[8][4];   // [ob][kt]  k rows indexed by PHYS h1 (phys==logical)
    #pragma unroll
    for (int ob = 0; ob < 8; ++ob) {
        const int col = (ob >> 1) * 32 + (cl >> 2) * 8 + (ob & 1) * 4 + (cl & 3);
        #pragma unroll
        for (int kt = 0; kt < 4; ++kt) {
            bf16x8 v;
            #pragma unroll
            for (int e = 0; e < 8; ++e)
                v[e] = (short)bf16r(W1[(kt * 32 + q * 8 + e) * HID + col]);
            w1t[ob][kt] = v;
        }
    }
    f32x4 b0q[8], b1q[8];
    #pragma unroll
    for (int ob = 0; ob < 8; ++ob) {
        #pragma unroll
        for (int r = 0; r < 4; ++r) {
            const int h = (ob >> 1) * 32 + q * 8 + (ob & 1) * 4 + r;
            b0q[ob][r] = b0[h];
            b1q[ob][r] = b1[h];
        }
    }
    bf16x8 w2f[4];      // L2 A-frag: row 0 = W2 (phys order), rows 1..15 = 0
    #pragma unroll
    for (int kt = 0; kt < 4; ++kt) {
        #pragma unroll
        for (int e = 0; e < 8; ++e)
            w2f[kt][e] = (cl == 0) ? (short)bf16r(W2[kt * 32 + q * 8 + e])
                                   : (short)0;
    }
    const float bias2 = b2[0];

    int c = blockIdx.x;

    // ---- prologue: stage chunk c into buf 0 (synchronous) ----
    {
        const int gp = c * 16 + p;
        const float fe0 = emb[gp];
        float2 xv0 = {0.f, 0.f};
        if (s == 0) xv0 = *(const float2*)(x + 2 * gp);
        const int e1 = (int)fe0;
        const int e2 = (e1 + 1 < NUMEMB) ? e1 + 1 : NUMEMB - 1;
        const float r = fe0 - (float)e1;
        const float4* p1 = (const float4*)(em_table + e1 * 32 + s * 8);
        const float4* p2 = (const float4*)(em_table + e2 * 32 + s * 8);
        const float4 a0v = p1[0], a1v = p1[1];
        const float4 c0v = p2[0], c1v = p2[1];
        uint4 d;
        d.x = pk2(a0v.x + (c0v.x - a0v.x) * r, a0v.y + (c0v.y - a0v.y) * r);
        d.y = pk2(a0v.z + (c0v.z - a0v.z) * r, a0v.w + (c0v.w - a0v.w) * r);
        d.z = pk2(a1v.x + (c1v.x - a1v.x) * r, a1v.y + (c1v.y - a1v.y) * r);
        d.w = pk2(a1v.z + (c1v.z - a1v.z) * r, a1v.w + (c1v.w - a1v.w) * r);
        *(uint4*)&A0[p * A0S + s * 8] = d;
        if (s == 0) *(unsigned*)&A0[p * A0S + 32] = pk2(xv0.x, xv0.y);
    }

    // ---- pipeline setup: state for chunks c+S (stage-next) and c+2S ----
    int cA = c + STRIDE;     if (cA > LASTC) cA = LASTC;
    int cB = c + 2 * STRIDE; if (cB > LASTC) cB = LASTC;
    const float feA = emb[cA * 16 + p];
    float feB = emb[cB * 16 + p];
    float2 xvA = {0.f, 0.f}, xvB = {0.f, 0.f};
    if (s == 0) {
        xvA = *(const float2*)(x + 2 * (cA * 16 + p));
        xvB = *(const float2*)(x + 2 * (cB * 16 + p));
    }
    float4 g1a, g1b, g2a, g2b;   // gathered em rows for chunk c+S
    float frA;
    {
        const int e1 = (int)feA;
        const int e2 = (e1 + 1 < NUMEMB) ? e1 + 1 : NUMEMB - 1;
        frA = feA - (float)e1;
        const float4* p1 = (const float4*)(em_table + e1 * 32 + s * 8);
        const float4* p2 = (const float4*)(em_table + e2 * 32 + s * 8);
        g1a = p1[0]; g1b = p1[1]; g2a = p2[0]; g2b = p2[1];
    }

    int buf = 0;
    for (; c < CHUNKS; c += STRIDE) {
        // 1. L0 B-frag reads for chunk c (written last iter; in-order DS)
        const int rowR = (buf * 16 + cl) * A0S;
        const bf16x8 bf0 = *(const bf16x8*)&A0[rowR + q * 8];
        const bf16x8 bf1 = *(const bf16x8*)&A0[rowR + 32 + q * 8];

        // 2. stage chunk c+S into buf^1 (fills the ds_read shadow)
        {
            const int rowW = ((buf ^ 1) * 16 + p) * A0S;
            uint4 d;
            d.x = pk2(g1a.x + (g2a.x - g1a.x) * frA, g1a.y + (g2a.y - g1a.y) * frA);
            d.y = pk2(g1a.z + (g2a.z - g1a.z) * frA, g1a.w + (g2a.w - g1a.w) * frA);
            d.z = pk2(g1b.x + (g2b.x - g1b.x) * frA, g1b.y + (g2b.y - g1b.y) * frA);
            d.w = pk2(g1b.z + (g2b.z - g1b.z) * frA, g1b.w + (g2b.w - g1b.w) * frA);
            *(uint4*)&A0[rowW + s * 8] = d;
            if (s == 0) *(unsigned*)&A0[rowW + 32] = pk2(xvA.x, xvA.y);
        }

        // 3. advance pipeline: gathers for c+2S (feB ready); scalars for c+3S
        {
            const int e1 = (int)feB;
            const int e2 = (e1 + 1 < NUMEMB) ? e1 + 1 : NUMEMB - 1;
            frA = feB - (float)e1;
            const float4* p1 = (const float4*)(em_table + e1 * 32 + s * 8);
            const float4* p2 = (const float4*)(em_table + e2 * 32 + s * 8);
            g1a = p1[0]; g1b = p1[1]; g2a = p2[0]; g2b = p2[1];
            xvA = xvB;
            int cC = c + 3 * STRIDE; if (cC > LASTC) cC = LASTC;
            feB = emb[cC * 16 + p];
            if (s == 0) xvB = *(const float2*)(x + 2 * (cC * 16 + p));
        }

        // 4. L0: all 128 h1 for this wave's 16 points, bias in C
        f32x4 acc[8];
        #pragma unroll
        for (int ob = 0; ob < 8; ++ob)
            acc[ob] = __builtin_amdgcn_mfma_f32_16x16x32_bf16(
                w0t[ob][0], bf0, b0q[ob], 0, 0, 0);
        #pragma unroll
        for (int ob = 0; ob < 8; ++ob)
            acc[ob] = __builtin_amdgcn_mfma_f32_16x16x32_bf16(
                w0t[ob][1], bf1, acc[ob], 0, 0, 0);

        // 5. pack h1: C/D frag pairs -> L1 B-frags, clamp fused (pk2c)
        bf16x8 h1f[4];
        #pragma unroll
        for (int kt = 0; kt < 4; ++kt) {
            const f32x4 v0 = acc[2 * kt], v1 = acc[2 * kt + 1];
            uint4 w;
            w.x = pk2c(v0[0], v0[1]);
            w.y = pk2c(v0[2], v0[3]);
            w.z = pk2c(v1[0], v1[1]);
            w.w = pk2c(v1[2], v1[3]);
            __builtin_memcpy(&h1f[kt], &w, 16);
        }

        // 6. L1: all register operands, bias in C at kt=0
        #pragma unroll
        for (int ob = 0; ob < 8; ++ob)
            acc[ob] = __builtin_amdgcn_mfma_f32_16x16x32_bf16(
                w1t[ob][0], h1f[0], b1q[ob], 0, 0, 0);
        #pragma unroll
        for (int kt = 1; kt < 4; ++kt)
            #pragma unroll
            for (int ob = 0; ob < 8; ++ob)
                acc[ob] = __builtin_amdgcn_mfma_f32_16x16x32_bf16(
                    w1t[ob][kt], h1f[kt], acc[ob], 0, 0, 0);

        // 7. pack h2 + L2 via MFMA (two parallel 2-chains), D[0][cl] = dot
        const f32x4 zero = {0.f, 0.f, 0.f, 0.f};
        f32x4 za = zero, zb = zero;
        #pragma unroll
        for (int kt = 0; kt < 4; ++kt) {
            const f32x4 v0 = acc[2 * kt], v1 = acc[2 * kt + 1];
            uint4 w;
            w.x = pk2c(v0[0], v0[1]);
            w.y = pk2c(v0[2], v0[3]);
            w.z = pk2c(v1[0], v1[1]);
            w.w = pk2c(v1[2], v1[3]);
            bf16x8 hf;
            __builtin_memcpy(&hf, &w, 16);
            if (kt < 2)
                za = __builtin_amdgcn_mfma_f32_16x16x32_bf16(w2f[kt], hf, za, 0, 0, 0);
            else
                zb = __builtin_amdgcn_mfma_f32_16x16x32_bf16(w2f[kt], hf, zb, 0, 0, 0);
        }
        const float z = za[0] + zb[0] + bias2;
        const float sig = __builtin_amdgcn_rcpf(1.f + __expf(-z));
        if (q == 0) out[c * 16 + cl] = sig;

        buf ^= 1;
    }
}

extern "C" void kernel_launch(void* const* d_in, const int* in_sizes, int n_in,
                              void* d_out, int out_size, void* d_ws, size_t ws_size,
                              hipStream_t stream) {
    const float* x   = (const float*)d_in[0];
    const float* emb = (const float*)d_in[1];
    const float* emt = (const float*)d_in[2];
    const float* W0  = (const float*)d_in[3];
    const float* b0  = (const float*)d_in[4];
    const float* W1  = (const float*)d_in[5];
    const float* b1  = (const float*)d_in[6];
    const float* W2  = (const float*)d_in[7];
    const float* b2  = (const float*)d_in[8];
    mlp_fused<<<NBLOCKS, 64, 0, stream>>>(x, emb, emt, W0, b0, W1, b1, W2, b2,
                                          (float*)d_out);
}